// Round 9
// baseline (631.947 us; speedup 1.0000x reference)
//
#include <hip/hip_runtime.h>
#include <stdint.h>

typedef __attribute__((ext_vector_type(8))) _Float16 half8;
typedef __attribute__((ext_vector_type(4))) _Float16 half4;
typedef __attribute__((ext_vector_type(4))) float floatx4;

#define NHEADS 16
#define HDIM   72
#define DPAD   80    // Q/K pad: cols 72..79 stored zero
#define DPADV  80    // V pad (5 n-blocks of 16; col 72 = ones for l-sum)
#define HID    1152
#define NQKV   3456
#define PP     4096
#define MR     8192   // B*P
#define LOG2E  1.44269504f

__device__ __forceinline__ float bf2f(unsigned short u) {
  union { unsigned int i; float f; } c; c.i = ((unsigned int)u) << 16; return c.f;
}
__device__ __forceinline__ unsigned short f2bf(float f) {
  union { float f; unsigned int i; } c; c.f = f;
  unsigned int x = c.i;
  x += ((x >> 16) & 1u) + 0x7fffu;   // RNE
  return (unsigned short)(x >> 16);
}
__device__ __forceinline__ float load_in(const void* p, long long i, int bf) {
  return bf ? bf2f(((const unsigned short*)p)[i]) : ((const float*)p)[i];
}

// async global->LDS copy, 16B per lane; LDS dest is wave-uniform base + lane*16
typedef const __attribute__((address_space(1))) void* gas_ptr;
typedef __attribute__((address_space(3))) void* las_ptr;
__device__ __forceinline__ void gload16(const _Float16* g, _Float16* l) {
  __builtin_amdgcn_global_load_lds((gas_ptr)g, (las_ptr)l, 16, 0, 0);
}

// ---------------- dtype detection (bf16 vs fp32 input buffers) --------------
__global__ __launch_bounds__(64) void k_detect(const void* hs, int* flag) {
  int lane = threadIdx.x;
  const unsigned short* u = (const unsigned short*)hs;
  int wild = 0;
  for (int t = 0; t < 8; ++t) {
    unsigned short v = u[lane * 8 + t];
    int e = (v >> 7) & 0xFF;
    if (e >= 134) wild++;
  }
  for (int off = 1; off < 64; off <<= 1) wild += __shfl_xor(wild, off);
  if (lane == 0) flag[0] = (wild > 32) ? 0 : 1;
}

// ---------------- prep: convert/transpose params to fp16 --------------------
__global__ __launch_bounds__(256) void k_prep(
    const void* hs, const void* cosp, const void* sinp,
    const void* wq, const void* wk, const void* wv, const void* wo,
    const void* qnw, const void* knw, const int* flag,
    _Float16* Xh, _Float16* Wqkv, _Float16* Wot,
    float* cosf, float* sinf, float* qw, float* kw) {
  int bf = flag[0];
  long long i = (long long)blockIdx.x * blockDim.x + threadIdx.x;
  const long long n0 = (long long)MR * HID;
  const long long n1 = (long long)NQKV * HID;
  const long long n2 = (long long)HID * HID;
  const long long n3 = (long long)2 * PP * HDIM;
  if (i < n0) { Xh[i] = (_Float16)load_in(hs, i, bf); return; }
  i -= n0;
  if (i < n1) {  // Wqkv^T[n][k] = W{q,k,v}[k][n%1152]
    long long n = i / HID, kk = i - n * HID;
    int sel = (int)(n / HID);
    long long nl = n - (long long)sel * HID;
    const void* W = (sel == 0) ? wq : ((sel == 1) ? wk : wv);
    Wqkv[i] = (_Float16)load_in(W, kk * HID + nl, bf);
    return;
  }
  i -= n1;
  if (i < n2) {  // Wo^T[n][k] = Wo[k][n]
    long long n = i / HID, kk = i - n * HID;
    Wot[i] = (_Float16)load_in(wo, kk * HID + n, bf);
    return;
  }
  i -= n2;
  if (i < n3) { cosf[i] = load_in(cosp, i, bf); return; }
  i -= n3;
  if (i < n3) { sinf[i] = load_in(sinp, i, bf); return; }
  i -= n3;
  if (i < HDIM) { qw[i] = load_in(qnw, i, bf); return; }
  i -= HDIM;
  if (i < HDIM) { kw[i] = load_in(knw, i, bf); return; }
}

// ---------------- fp16 MFMA GEMM: C[M,N] = A[M,K] * Bt[N,K]^T ---------------
// mode 0: fp16 out to outp. mode 1: out per detected dtype to outp.
// m97 structure: linear [128][32] LDS staged via global_load_lds width=16
// (no reg round-trip), 2 barriers per K-step, 8 blocks/CU for TLP overlap.
// T1 XCD swizzle: gridDim.y % 8 == 0 required; row-bands pin per XCD.
#define BK 32
__global__ __launch_bounds__(256) void k_gemm(
    const _Float16* __restrict__ A, const _Float16* __restrict__ Bt,
    int N, int K, int mode, const int* __restrict__ flag,
    void* __restrict__ outp) {
  __shared__ _Float16 As[128 * BK];   // 8 KB
  __shared__ _Float16 Bs[128 * BK];   // 8 KB
  int tid = threadIdx.x;
  int wave = tid >> 6, lane = tid & 63;
  int quad = lane >> 4, l16 = lane & 15;

  // bijective XCD-aware remap: same-XCD blocks form an 8-row band sharing A
  int lin = blockIdx.y * gridDim.x + blockIdx.x;
  int xcd = lin & 7;
  int j = lin >> 3;
  int nbx = gridDim.x;
  int rows_per = gridDim.y >> 3;
  int by = xcd * rows_per + j / nbx;
  int bx = j - (j / nbx) * nbx;
  int bM = by * 128, bN = bx * 128;

  int wm = (wave & 1) * 64, wn = (wave >> 1) * 64;
  int qk = quad * 8;

  floatx4 acc[4][4];
  floatx4 z4 = {0.f, 0.f, 0.f, 0.f};
#pragma unroll
  for (int i = 0; i < 4; ++i)
#pragma unroll
    for (int jj = 0; jj < 4; ++jj) acc[i][jj] = z4;

  // staging: tile = 128 rows x 32 halves = 512 x 16B chunks; thread owns
  // chunks tid and tid+256: row = c>>2, col = (c&3)*8. LDS dest is linear
  // (chunk c -> byte c*16), wave-uniform base = wave*64 chunks.
  const _Float16* gA0 = A  + (size_t)(bM + (tid >> 2)) * K + (tid & 3) * 8;
  const _Float16* gB0 = Bt + (size_t)(bN + (tid >> 2)) * K + (tid & 3) * 8;
  const _Float16* gA1 = gA0 + (size_t)64 * K;
  const _Float16* gB1 = gB0 + (size_t)64 * K;
  _Float16* lA = As + wave * 512;   // wave*64 chunks * 8 halves/chunk
  _Float16* lB = Bs + wave * 512;

  for (int k0 = 0; k0 < K; k0 += BK) {
    __syncthreads();                  // prior-iter frag reads complete
    gload16(gA0, lA);
    gload16(gA1, lA + 2048);          // +256 chunks
    gload16(gB0, lB);
    gload16(gB1, lB + 2048);
    gA0 += BK; gA1 += BK; gB0 += BK; gB1 += BK;
    __syncthreads();                  // compiler drains vmcnt before barrier

    half8 af[4], bfv[4];
#pragma unroll
    for (int i = 0; i < 4; ++i)
      af[i] = *(const half8*)(As + (wm + i * 16 + l16) * BK + qk);
#pragma unroll
    for (int jj = 0; jj < 4; ++jj)
      bfv[jj] = *(const half8*)(Bs + (wn + jj * 16 + l16) * BK + qk);
#pragma unroll
    for (int i = 0; i < 4; ++i)
#pragma unroll
      for (int jj = 0; jj < 4; ++jj)
        acc[i][jj] = __builtin_amdgcn_mfma_f32_16x16x32_f16(af[i], bfv[jj], acc[i][jj], 0, 0, 0);
  }

  if (mode == 0) {
#pragma unroll
    for (int i = 0; i < 4; ++i)
#pragma unroll
      for (int jj = 0; jj < 4; ++jj)
#pragma unroll
        for (int r = 0; r < 4; ++r) {
          size_t row = (size_t)(bM + wm + i * 16 + quad * 4 + r);
          size_t col = (size_t)(bN + wn + jj * 16 + l16);
          ((_Float16*)outp)[row * N + col] = (_Float16)acc[i][jj][r];
        }
  } else {
    int obf = flag[0];
#pragma unroll
    for (int i = 0; i < 4; ++i)
#pragma unroll
      for (int jj = 0; jj < 4; ++jj)
#pragma unroll
        for (int r = 0; r < 4; ++r) {
          size_t row = (size_t)(bM + wm + i * 16 + quad * 4 + r);
          size_t col = (size_t)(bN + wn + jj * 16 + l16);
          float v = acc[i][jj][r];
          if (obf) ((unsigned short*)outp)[row * N + col] = f2bf(v);
          else     ((float*)outp)[row * N + col] = v;
        }
  }
}

// ---------------- per-head RMSNorm + 2D RoPE (fp32 math, fp16 out) ----------
// 4 waves/block, one (row m, head h) per wave. QKV input is fp16.
// Q is pre-scaled by log2(e) so k_flash softmax runs in exp2 domain.
__global__ __launch_bounds__(256) void k_norm_rope(
    const _Float16* __restrict__ QKV, const float* __restrict__ cosf,
    const float* __restrict__ sinf, const float* __restrict__ qw,
    const float* __restrict__ kw,
    _Float16* __restrict__ Qp, _Float16* __restrict__ Kp,
    _Float16* __restrict__ Vp) {
  int wave = threadIdx.x >> 6, lane = threadIdx.x & 63;
  int bid = blockIdx.x * 4 + wave;
  int m = bid >> 4, h = bid & 15;
  int b = m >> 12, p = m & 4095;
  __shared__ float sq[4][HDIM], sk[4][HDIM];

  const _Float16* rowp = QKV + (long long)m * NQKV + h * HDIM;
  int i0 = lane, i1 = lane + 64;
  bool has1 = (i1 < HDIM);
  float q0 = (float)rowp[i0];
  float k0 = (float)rowp[1152 + i0];
  float v0 = (float)rowp[2304 + i0];
  float q1 = 0.f, k1 = 0.f, v1 = 0.f;
  if (has1) { q1 = (float)rowp[i1]; k1 = (float)rowp[1152 + i1]; v1 = (float)rowp[2304 + i1]; }

  float sq_s = q0 * q0 + q1 * q1;
  float sk_s = k0 * k0 + k1 * k1;
  float sv_s = v0 * v0 + v1 * v1;
  for (int off = 1; off < 64; off <<= 1) {
    sq_s += __shfl_xor(sq_s, off);
    sk_s += __shfl_xor(sk_s, off);
    sv_s += __shfl_xor(sv_s, off);
  }
  float rq = rsqrtf(sq_s / 72.f + 1e-6f);
  float rk = rsqrtf(sk_s / 72.f + 1e-6f);
  float rv = rsqrtf(sv_s / 72.f + 1e-6f);

  sq[wave][i0] = q0 * rq * qw[i0];
  sk[wave][i0] = k0 * rk * kw[i0];
  if (has1) { sq[wave][i1] = q1 * rq * qw[i1]; sk[wave][i1] = k1 * rk * kw[i1]; }
  __syncthreads();

  const float* crow = cosf + (long long)m * HDIM;
  const float* srow = sinf + (long long)m * HDIM;
  long long obase = ((long long)(b * NHEADS + h) * PP + p) * DPAD;
  long long obV   = ((long long)(b * NHEADS + h) * PP + p) * DPADV;
#pragma unroll
  for (int t = 0; t < 2; ++t) {
    int i = lane + t * 64;
    if (i < DPAD) {
      _Float16 qv = (_Float16)0.f, kv = (_Float16)0.f;
      if (i < HDIM) {
        int j = (i >= 36) ? (i - 36) : i;
        float c = crow[i], s = srow[i];
        float qo, ko;
        if (j < 18) { qo = sq[wave][i] * c - sq[wave][i + 18] * s; ko = sk[wave][i] * c - sk[wave][i + 18] * s; }
        else        { qo = sq[wave][i] * c + sq[wave][i - 18] * s; ko = sk[wave][i] * c + sk[wave][i - 18] * s; }
        qv = (_Float16)(qo * LOG2E); kv = (_Float16)ko;
      }
      Qp[obase + i] = qv; Kp[obase + i] = kv;
    }
    if (i < DPADV) {
      _Float16 vv = (_Float16)0.f;
      if (i < HDIM) vv = (_Float16)(((t == 0) ? v0 : v1) * rv);
      Vp[obV + i] = vv;
    }
  }
}

// ---------------- V transpose: [bh][p][80] -> [bh][80][4096], d=72 := 1 ----
// Ones in row 72 make PV's column 72 accumulate the softmax denominator.
__global__ __launch_bounds__(256) void k_vtrans(
    const _Float16* __restrict__ Vp, _Float16* __restrict__ VtG) {
  __shared__ _Float16 T[DPADV * 72];
  int tid = threadIdx.x;
  int pt = blockIdx.x, bh = blockIdx.y;
  long long src = (long long)bh * PP * DPADV + (long long)pt * 64 * DPADV;
#pragma unroll
  for (int pp = 0; pp < 3; ++pp) {
    int c = tid + pp * 256;
    if (c < 640) {
      int r = c / 10, ds = c % 10;
      half8 v = *(const half8*)(Vp + src + r * DPADV + ds * 8);
#pragma unroll
      for (int j = 0; j < 8; ++j) T[(ds * 8 + j) * 72 + r] = v[j];
    }
  }
  __syncthreads();
  long long dst = (long long)bh * DPADV * PP + (long long)pt * 64;
#pragma unroll
  for (int pp = 0; pp < 3; ++pp) {
    int c = tid + pp * 256;
    if (c < 640) {
      int d = c >> 3, ps = (c & 7) * 8;
      half8 v = *(const half8*)(T + d * 72 + ps);
      if (d == 72) {
#pragma unroll
        for (int j = 0; j < 8; ++j) v[j] = (_Float16)1.f;
      }
      *(half8*)(VtG + dst + (long long)d * PP + ps) = v;
    }
  }
}

// ---------------- flash attention: TQ=128, V^T pre-staged, MFMA l-sum -------
// Block: 256 thr (4 waves), each wave 32 q-rows (2 row-blocks of 16), TK=64.
// S computed TRANSPOSED (mfma(K,Q)); Q pre-scaled by log2e -> exp2 softmax
// via raw v_exp_f32 (__builtin_amdgcn_exp2f; plain exp2f is slow libm).
// K-dim 80 via 3x mfma_x32, third chunk quad-predicated (only proven layout).
// Grid: x = head (pins all q-tiles of a head to one XCD), y = q-tile.
#define TK 64
#define NT (PP / TK)
#define LDK 80    // K rows, no pad (stride 160 B, 16B-aligned)
#define LDV 72    // V^T 80x72, P 32x72/wave
__global__ __launch_bounds__(256) void k_flash(
    const _Float16* __restrict__ Qp, const _Float16* __restrict__ Kp,
    const _Float16* __restrict__ VtG, _Float16* __restrict__ Oat) {
  __shared__ _Float16 Kl[TK * LDK];         // 10,240 B
  __shared__ _Float16 Vt[DPADV * LDV];      // 11,520 B
  __shared__ _Float16 Pl[128 * LDV];        // 18,432 B
  int tid = threadIdx.x, wave = tid >> 6, lane = tid & 63;
  int quad = lane >> 4, l16 = lane & 15;
  int bh = blockIdx.x, qt = blockIdx.y;
  const long long headoff = (long long)bh * PP * DPAD;
  const long long vhead   = (long long)bh * DPADV * PP;

  half8 zh8;
#pragma unroll
  for (int j = 0; j < 8; ++j) zh8[j] = (_Float16)0.f;

  half8 qf[2][3];
#pragma unroll
  for (int mb = 0; mb < 2; ++mb) {
    int qrow = qt * 128 + wave * 32 + mb * 16 + l16;
    const _Float16* qp = Qp + headoff + (long long)qrow * DPAD;
#pragma unroll
    for (int ck = 0; ck < 2; ++ck)
      qf[mb][ck] = *(const half8*)(qp + ck * 32 + quad * 8);
    qf[mb][2] = zh8;
    if (quad < 2) qf[mb][2] = *(const half8*)(qp + 64 + quad * 8);
  }

  floatx4 O[2][5];
  floatx4 z4 = {0.f, 0.f, 0.f, 0.f};
#pragma unroll
  for (int mb = 0; mb < 2; ++mb)
#pragma unroll
    for (int d = 0; d < 5; ++d) O[mb][d] = z4;
  float m_i[2];
  m_i[0] = -1e30f; m_i[1] = -1e30f;
  _Float16* Pw = Pl + wave * 32 * LDV;

  // T14 async-STAGE: global->reg issue early, reg->LDS write after barrier.
  half8 kreg[3], vreg[3];
  {
    const _Float16* Ksrc = Kp + headoff;
    const _Float16* Vsrc = VtG + vhead;
#pragma unroll
    for (int pp = 0; pp < 3; ++pp) {
      int c = tid + pp * 256;
      if (c < 640)
        kreg[pp] = *(const half8*)(Ksrc + c * 8);
    }
#pragma unroll
    for (int pp = 0; pp < 3; ++pp) {
      int c = tid + pp * 256;
      if (c < 640)
        vreg[pp] = *(const half8*)(Vsrc + (long long)(c >> 3) * PP + (c & 7) * 8);
    }
  }

  for (int kt = 0; kt < NT; ++kt) {
    __syncthreads();   // prior-iter reads of Kl/Vt done before restaging
#pragma unroll
    for (int pp = 0; pp < 3; ++pp) {        // K: 640 16B chunks (64x80)
      int c = tid + pp * 256;
      if (c < 640)
        *(half8*)(Kl + (c / 10) * LDK + (c % 10) * 8) = kreg[pp];
    }
#pragma unroll
    for (int pp = 0; pp < 3; ++pp) {        // V^T: 640 16B chunks (80x64)
      int c = tid + pp * 256;
      if (c < 640)
        *(half8*)(Vt + (c >> 3) * LDV + (c & 7) * 8) = vreg[pp];
    }
    __syncthreads();

    // issue next tile's global loads; latency hides under compute below
    {
      int ktn = (kt + 1 < NT) ? kt + 1 : kt;
      const _Float16* Ksrc = Kp + headoff + (long long)ktn * TK * DPAD;
      const _Float16* Vsrc = VtG + vhead + ktn * TK;
#pragma unroll
      for (int pp = 0; pp < 3; ++pp) {
        int c = tid + pp * 256;
        if (c < 640)
          kreg[pp] = *(const half8*)(Ksrc + c * 8);
      }
#pragma unroll
      for (int pp = 0; pp < 3; ++pp) {
        int c = tid + pp * 256;
        if (c < 640)
          vreg[pp] = *(const half8*)(Vsrc + (long long)(c >> 3) * PP + (c & 7) * 8);
      }
    }

    // S^T = K Q^T: lane holds S[q = mb*16+l16][key = nb*16+quad*4+r]
    floatx4 sb[2][4];
    __builtin_amdgcn_s_setprio(1);
#pragma unroll
    for (int nb = 0; nb < 4; ++nb) {
      const _Float16* kp = Kl + (nb * 16 + l16) * LDK;
      half8 kf0 = *(const half8*)(kp + quad * 8);
      half8 kf1 = *(const half8*)(kp + 32 + quad * 8);
      half8 kf2 = zh8;
      if (quad < 2) kf2 = *(const half8*)(kp + 64 + quad * 8);
#pragma unroll
      for (int mb = 0; mb < 2; ++mb) {
        floatx4 a = __builtin_amdgcn_mfma_f32_16x16x32_f16(kf0, qf[mb][0], z4, 0, 0, 0);
        a = __builtin_amdgcn_mfma_f32_16x16x32_f16(kf1, qf[mb][1], a, 0, 0, 0);
        a = __builtin_amdgcn_mfma_f32_16x16x32_f16(kf2, qf[mb][2], a, 0, 0, 0);
        sb[mb][nb] = a;
      }
    }
    __builtin_amdgcn_s_setprio(0);

    // online softmax in exp2 domain (Q pre-scaled by log2e).
    // Max via nested fmax triples -> v_max3_f32 (T17).
    // T13 defer-max: skip O-rescale while tile max stays within 11.5 of m_i.
#pragma unroll
    for (int mb = 0; mb < 2; ++mb) {
      float t1 = fmaxf(fmaxf(sb[mb][0][0], sb[mb][0][1]), sb[mb][0][2]);
      float t2 = fmaxf(fmaxf(sb[mb][0][3], sb[mb][1][0]), sb[mb][1][1]);
      float t3 = fmaxf(fmaxf(sb[mb][1][2], sb[mb][1][3]), sb[mb][2][0]);
      float t4 = fmaxf(fmaxf(sb[mb][2][1], sb[mb][2][2]), sb[mb][2][3]);
      float t5 = fmaxf(fmaxf(sb[mb][3][0], sb[mb][3][1]), sb[mb][3][2]);
      float t = fmaxf(fmaxf(t1, t2), t3);
      t = fmaxf(fmaxf(t, t4), t5);
      t = fmaxf(t, sb[mb][3][3]);
      t = fmaxf(t, __shfl_xor(t, 16));
      t = fmaxf(t, __shfl_xor(t, 32));
      if (!__all(t <= m_i[mb] + 11.5f)) {
        float mnew = fmaxf(m_i[mb], t);
        float al = __builtin_amdgcn_exp2f(m_i[mb] - mnew);
        m_i[mb] = mnew;
        // transpose al (per q=l16) to O's row axis (q=quad*4+r): source lane
        // (same quad group) with l16 == quad*4+r holds that row's factor.
        float alT[4];
#pragma unroll
        for (int r = 0; r < 4; ++r)
          alT[r] = __shfl(al, (lane & 48) + quad * 4 + r);
#pragma unroll
        for (int d = 0; d < 5; ++d)
#pragma unroll
          for (int r = 0; r < 4; ++r) O[mb][d][r] *= alT[r];
      }
      float mi = m_i[mb];
      // P write: 4 consecutive keys per lane -> one b64 per (mb,nb)
#pragma unroll
      for (int nb = 0; nb < 4; ++nb) {
        half4 w;
#pragma unroll
        for (int r = 0; r < 4; ++r)
          w[r] = (_Float16)__builtin_amdgcn_exp2f(sb[mb][nb][r] - mi);
        *(half4*)(Pw + (mb * 16 + l16) * LDV + nb * 16 + quad * 4) = w;
      }
    }

    // O += P V  (V-frags reused across mb; col 72 accumulates l)
    __builtin_amdgcn_s_setprio(1);
#pragma unroll
    for (int ck2 = 0; ck2 < 2; ++ck2) {
      half8 pf0 = *(const half8*)(Pw + l16 * LDV + ck2 * 32 + quad * 8);
      half8 pf1 = *(const half8*)(Pw + (16 + l16) * LDV + ck2 * 32 + quad * 8);
#pragma unroll
      for (int d = 0; d < 5; ++d) {
        half8 vf = *(const half8*)(Vt + (d * 16 + l16) * LDV + ck2 * 32 + quad * 8);
        O[0][d] = __builtin_amdgcn_mfma_f32_16x16x32_f16(pf0, vf, O[0][d], 0, 0, 0);
        O[1][d] = __builtin_amdgcn_mfma_f32_16x16x32_f16(pf1, vf, O[1][d], 0, 0, 0);
      }
    }
    __builtin_amdgcn_s_setprio(0);
  }

  // epilogue: l lives in O[mb][4] at l16==8; broadcast within quad, divide.
  int b = bh >> 4, h = bh & 15;
  int src = (lane & 48) + 8;
#pragma unroll
  for (int mb = 0; mb < 2; ++mb) {
    float linv[4];
#pragma unroll
    for (int r = 0; r < 4; ++r)
      linv[r] = 1.f / __shfl(O[mb][4][r], src);
    long long orow = (long long)b * PP + qt * 128 + wave * 32 + mb * 16 + quad * 4;
#pragma unroll
    for (int d = 0; d < 5; ++d) {
      int dd = d * 16 + l16;
      if (dd < HDIM) {
#pragma unroll
        for (int r = 0; r < 4; ++r)
          Oat[(orow + r) * HID + h * HDIM + dd] = (_Float16)(O[mb][d][r] * linv[r]);
      }
    }
  }
}

// ---------------------------------------------------------------------------
extern "C" void kernel_launch(void* const* d_in, const int* in_sizes, int n_in,
                              void* d_out, int out_size, void* d_ws, size_t ws_size,
                              hipStream_t stream) {
  (void)in_sizes; (void)n_in; (void)out_size; (void)ws_size;
  const void* hs   = d_in[0];
  const void* cosp = d_in[1];
  const void* sinp = d_in[2];
  const void* wq   = d_in[3];
  const void* wk   = d_in[4];
  const void* wv   = d_in[5];
  const void* wo   = d_in[6];
  const void* qnw  = d_in[7];
  const void* knw  = d_in[8];

  char* ws = (char*)d_ws;
  size_t off = 0;
  auto take = [&](size_t bytes) -> char* {
    off = (off + 255) & ~(size_t)255;
    char* p = ws + off; off += bytes; return p;
  };
  int* flag        = (int*)take(4);
  _Float16* Xh     = (_Float16*)take((size_t)MR * HID * 2);     // 18.9 MB
  _Float16* Wqkvh  = (_Float16*)take((size_t)NQKV * HID * 2);   // 8.0 MB
  _Float16* Woth   = (_Float16*)take((size_t)HID * HID * 2);    // 2.65 MB
  float* cosf_     = (float*)take((size_t)2 * PP * HDIM * 4);
  float* sinf_     = (float*)take((size_t)2 * PP * HDIM * 4);
  float* qwf       = (float*)take(HDIM * 4);
  float* kwf       = (float*)take(HDIM * 4);
  _Float16* QKVh   = (_Float16*)take((size_t)MR * NQKV * 2);    // 56.6 MB
  _Float16* Kp     = (_Float16*)take((size_t)2 * NHEADS * PP * DPAD * 2);   // 21.0 MB
  _Float16* Vp     = (_Float16*)take((size_t)2 * NHEADS * PP * DPADV * 2);  // 21.0 MB
  // Aliases over dead regions (sequential stream, graph-safe):
  //  - Qp reuses Xh+Wqkvh (26.9 MB >= 21.0 MB; both dead after QKV GEMM)
  //  - Oat reuses QKVh[0 .. 18.9 MB) (QKVh dead after k_norm_rope)
  //  - VtG reuses QKVh[20 MB .. 41 MB) (past Oat, within QKVh's 56.6 MB)
  _Float16* Qp  = Xh;
  _Float16* Oat = QKVh;
  _Float16* VtG = (_Float16*)((char*)QKVh + (size_t)20 * 1024 * 1024);

  k_detect<<<dim3(1), dim3(64), 0, stream>>>(hs, flag);

  long long totalPrep = (long long)MR * HID + (long long)NQKV * HID +
                        (long long)HID * HID + 2LL * 2 * PP * HDIM + 2 * HDIM;
  int prepBlocks = (int)((totalPrep + 255) / 256);
  k_prep<<<dim3(prepBlocks), dim3(256), 0, stream>>>(
      hs, cosp, sinp, wq, wk, wv, wo, qnw, knw, flag,
      Xh, Wqkvh, Woth, cosf_, sinf_, qwf, kwf);

  // QKV = X @ [Wq|Wk|Wv]  (fp16 inputs, fp32 accum, fp16 out)
  k_gemm<<<dim3(NQKV / 128, MR / 128), dim3(256), 0, stream>>>(
      Xh, Wqkvh, NQKV, HID, 0, flag, QKVh);

  k_norm_rope<<<dim3(MR * NHEADS / 4), dim3(256), 0, stream>>>(
      QKVh, cosf_, sinf_, qwf, kwf, Qp, Kp, Vp);

  k_vtrans<<<dim3(PP / 64, 2 * NHEADS), dim3(256), 0, stream>>>(Vp, VtG);

  k_flash<<<dim3(2 * NHEADS, PP / 128), dim3(256), 0, stream>>>(Qp, Kp, VtG, Oat);

  // out = attnout @ Wo  (fp16 inputs, output per detected dtype)
  k_gemm<<<dim3(HID / 128, MR / 128), dim3(256), 0, stream>>>(
      Oat, Woth, HID, HID, 1, flag, d_out);
}

// Round 10
// 607.663 us; speedup vs baseline: 1.0400x; 1.0400x over previous
//
#include <hip/hip_runtime.h>
#include <stdint.h>

typedef __attribute__((ext_vector_type(8))) _Float16 half8;
typedef __attribute__((ext_vector_type(4))) _Float16 half4;
typedef __attribute__((ext_vector_type(4))) float floatx4;

#define NHEADS 16
#define HDIM   72
#define DPAD   80    // Q/K pad: cols 72..79 stored zero
#define DPADV  80    // V pad (5 n-blocks of 16; col 72 = ones for l-sum)
#define HID    1152
#define NQKV   3456
#define PP     4096
#define MR     8192   // B*P
#define LOG2E  1.44269504f

__device__ __forceinline__ float bf2f(unsigned short u) {
  union { unsigned int i; float f; } c; c.i = ((unsigned int)u) << 16; return c.f;
}
__device__ __forceinline__ unsigned short f2bf(float f) {
  union { float f; unsigned int i; } c; c.f = f;
  unsigned int x = c.i;
  x += ((x >> 16) & 1u) + 0x7fffu;   // RNE
  return (unsigned short)(x >> 16);
}
__device__ __forceinline__ float load_in(const void* p, long long i, int bf) {
  return bf ? bf2f(((const unsigned short*)p)[i]) : ((const float*)p)[i];
}

// ---------------- dtype detection (bf16 vs fp32 input buffers) --------------
__global__ __launch_bounds__(64) void k_detect(const void* hs, int* flag) {
  int lane = threadIdx.x;
  const unsigned short* u = (const unsigned short*)hs;
  int wild = 0;
  for (int t = 0; t < 8; ++t) {
    unsigned short v = u[lane * 8 + t];
    int e = (v >> 7) & 0xFF;
    if (e >= 134) wild++;
  }
  for (int off = 1; off < 64; off <<= 1) wild += __shfl_xor(wild, off);
  if (lane == 0) flag[0] = (wild > 32) ? 0 : 1;
}

// ---------------- prep: convert/transpose params to fp16 --------------------
__global__ __launch_bounds__(256) void k_prep(
    const void* hs, const void* cosp, const void* sinp,
    const void* wq, const void* wk, const void* wv, const void* wo,
    const void* qnw, const void* knw, const int* flag,
    _Float16* Xh, _Float16* Wqkv, _Float16* Wot,
    float* cosf, float* sinf, float* qw, float* kw) {
  int bf = flag[0];
  long long i = (long long)blockIdx.x * blockDim.x + threadIdx.x;
  const long long n0 = (long long)MR * HID;
  const long long n1 = (long long)NQKV * HID;
  const long long n2 = (long long)HID * HID;
  const long long n3 = (long long)2 * PP * HDIM;
  if (i < n0) { Xh[i] = (_Float16)load_in(hs, i, bf); return; }
  i -= n0;
  if (i < n1) {  // Wqkv^T[n][k] = W{q,k,v}[k][n%1152]
    long long n = i / HID, kk = i - n * HID;
    int sel = (int)(n / HID);
    long long nl = n - (long long)sel * HID;
    const void* W = (sel == 0) ? wq : ((sel == 1) ? wk : wv);
    Wqkv[i] = (_Float16)load_in(W, kk * HID + nl, bf);
    return;
  }
  i -= n1;
  if (i < n2) {  // Wo^T[n][k] = Wo[k][n]
    long long n = i / HID, kk = i - n * HID;
    Wot[i] = (_Float16)load_in(wo, kk * HID + n, bf);
    return;
  }
  i -= n2;
  if (i < n3) { cosf[i] = load_in(cosp, i, bf); return; }
  i -= n3;
  if (i < n3) { sinf[i] = load_in(sinp, i, bf); return; }
  i -= n3;
  if (i < HDIM) { qw[i] = load_in(qnw, i, bf); return; }
  i -= HDIM;
  if (i < HDIM) { kw[i] = load_in(knw, i, bf); return; }
}

// ---------------- fp16 MFMA GEMM: C[M,N] = A[M,K] * Bt[N,K]^T ---------------
// mode 0: fp16 out to outp. mode 1: out per detected dtype to outp.
// T3-lite pipeline: regs preloaded; per iter {bar; LDS-write; bar; issue
// next loads; MFMA} so global latency hides under compute. (Round-9 A/B:
// global_load_lds-direct without counted-vmcnt pipelining is SLOWER than
// this reg-staged prefetch — keep this structure.)
// T1 XCD swizzle: gridDim.y % 8 == 0 required; row-bands pin per XCD.
#define LDA 40
__global__ __launch_bounds__(256) void k_gemm(
    const _Float16* __restrict__ A, const _Float16* __restrict__ Bt,
    int N, int K, int mode, const int* __restrict__ flag,
    void* __restrict__ outp) {
  __shared__ _Float16 As[128 * LDA];
  __shared__ _Float16 Bs[128 * LDA];
  int tid = threadIdx.x;
  int wave = tid >> 6, lane = tid & 63;
  int quad = lane >> 4, l16 = lane & 15;

  // bijective XCD-aware remap: same-XCD blocks form an 8-row band sharing A
  int lin = blockIdx.y * gridDim.x + blockIdx.x;
  int xcd = lin & 7;
  int j = lin >> 3;
  int nbx = gridDim.x;
  int rows_per = gridDim.y >> 3;
  int by = xcd * rows_per + j / nbx;
  int bx = j - (j / nbx) * nbx;
  int bM = by * 128, bN = bx * 128;

  int wm = (wave & 1) * 64, wn = (wave >> 1) * 64;
  int qk = quad * 8;
  int sr = tid >> 1, sc = (tid & 1) * 16;

  floatx4 acc[4][4];
  floatx4 z4 = {0.f, 0.f, 0.f, 0.f};
#pragma unroll
  for (int i = 0; i < 4; ++i)
#pragma unroll
    for (int jj = 0; jj < 4; ++jj) acc[i][jj] = z4;

  const _Float16* gA = A + (size_t)(bM + sr) * K + sc;
  const _Float16* gB = Bt + (size_t)(bN + sr) * K + sc;

  half8 a0 = *(const half8*)(gA);
  half8 a1 = *(const half8*)(gA + 8);
  half8 b0 = *(const half8*)(gB);
  half8 b1 = *(const half8*)(gB + 8);
  gA += 32; gB += 32;

  for (int k0 = 0; k0 < K; k0 += 32) {
    __syncthreads();
    *(half8*)(As + sr * LDA + sc)     = a0;
    *(half8*)(As + sr * LDA + sc + 8) = a1;
    *(half8*)(Bs + sr * LDA + sc)     = b0;
    *(half8*)(Bs + sr * LDA + sc + 8) = b1;
    __syncthreads();
    if (k0 + 32 < K) {
      a0 = *(const half8*)(gA);
      a1 = *(const half8*)(gA + 8);
      b0 = *(const half8*)(gB);
      b1 = *(const half8*)(gB + 8);
      gA += 32; gB += 32;
    }
    half8 af[4], bfv[4];
#pragma unroll
    for (int i = 0; i < 4; ++i)
      af[i] = *(const half8*)(As + (wm + i * 16 + l16) * LDA + qk);
#pragma unroll
    for (int jj = 0; jj < 4; ++jj)
      bfv[jj] = *(const half8*)(Bs + (wn + jj * 16 + l16) * LDA + qk);
#pragma unroll
    for (int i = 0; i < 4; ++i)
#pragma unroll
      for (int jj = 0; jj < 4; ++jj)
        acc[i][jj] = __builtin_amdgcn_mfma_f32_16x16x32_f16(af[i], bfv[jj], acc[i][jj], 0, 0, 0);
  }

  if (mode == 0) {
#pragma unroll
    for (int i = 0; i < 4; ++i)
#pragma unroll
      for (int jj = 0; jj < 4; ++jj)
#pragma unroll
        for (int r = 0; r < 4; ++r) {
          size_t row = (size_t)(bM + wm + i * 16 + quad * 4 + r);
          size_t col = (size_t)(bN + wn + jj * 16 + l16);
          ((_Float16*)outp)[row * N + col] = (_Float16)acc[i][jj][r];
        }
  } else {
    int obf = flag[0];
#pragma unroll
    for (int i = 0; i < 4; ++i)
#pragma unroll
      for (int jj = 0; jj < 4; ++jj)
#pragma unroll
        for (int r = 0; r < 4; ++r) {
          size_t row = (size_t)(bM + wm + i * 16 + quad * 4 + r);
          size_t col = (size_t)(bN + wn + jj * 16 + l16);
          float v = acc[i][jj][r];
          if (obf) ((unsigned short*)outp)[row * N + col] = f2bf(v);
          else     ((float*)outp)[row * N + col] = v;
        }
  }
}

// ---------------- per-head RMSNorm + 2D RoPE (fp32 math, fp16 out) ----------
// 4 waves/block, one (row m, head h) per wave. QKV input is fp16.
// Q is pre-scaled by log2(e) so k_flash softmax runs in exp2 domain.
__global__ __launch_bounds__(256) void k_norm_rope(
    const _Float16* __restrict__ QKV, const float* __restrict__ cosf,
    const float* __restrict__ sinf, const float* __restrict__ qw,
    const float* __restrict__ kw,
    _Float16* __restrict__ Qp, _Float16* __restrict__ Kp,
    _Float16* __restrict__ Vp) {
  int wave = threadIdx.x >> 6, lane = threadIdx.x & 63;
  int bid = blockIdx.x * 4 + wave;
  int m = bid >> 4, h = bid & 15;
  int b = m >> 12, p = m & 4095;
  __shared__ float sq[4][HDIM], sk[4][HDIM];

  const _Float16* rowp = QKV + (long long)m * NQKV + h * HDIM;
  int i0 = lane, i1 = lane + 64;
  bool has1 = (i1 < HDIM);
  float q0 = (float)rowp[i0];
  float k0 = (float)rowp[1152 + i0];
  float v0 = (float)rowp[2304 + i0];
  float q1 = 0.f, k1 = 0.f, v1 = 0.f;
  if (has1) { q1 = (float)rowp[i1]; k1 = (float)rowp[1152 + i1]; v1 = (float)rowp[2304 + i1]; }

  float sq_s = q0 * q0 + q1 * q1;
  float sk_s = k0 * k0 + k1 * k1;
  float sv_s = v0 * v0 + v1 * v1;
  for (int off = 1; off < 64; off <<= 1) {
    sq_s += __shfl_xor(sq_s, off);
    sk_s += __shfl_xor(sk_s, off);
    sv_s += __shfl_xor(sv_s, off);
  }
  float rq = rsqrtf(sq_s / 72.f + 1e-6f);
  float rk = rsqrtf(sk_s / 72.f + 1e-6f);
  float rv = rsqrtf(sv_s / 72.f + 1e-6f);

  sq[wave][i0] = q0 * rq * qw[i0];
  sk[wave][i0] = k0 * rk * kw[i0];
  if (has1) { sq[wave][i1] = q1 * rq * qw[i1]; sk[wave][i1] = k1 * rk * kw[i1]; }
  __syncthreads();

  const float* crow = cosf + (long long)m * HDIM;
  const float* srow = sinf + (long long)m * HDIM;
  long long obase = ((long long)(b * NHEADS + h) * PP + p) * DPAD;
  long long obV   = ((long long)(b * NHEADS + h) * PP + p) * DPADV;
#pragma unroll
  for (int t = 0; t < 2; ++t) {
    int i = lane + t * 64;
    if (i < DPAD) {
      _Float16 qv = (_Float16)0.f, kv = (_Float16)0.f;
      if (i < HDIM) {
        int j = (i >= 36) ? (i - 36) : i;
        float c = crow[i], s = srow[i];
        float qo, ko;
        if (j < 18) { qo = sq[wave][i] * c - sq[wave][i + 18] * s; ko = sk[wave][i] * c - sk[wave][i + 18] * s; }
        else        { qo = sq[wave][i] * c + sq[wave][i - 18] * s; ko = sk[wave][i] * c + sk[wave][i - 18] * s; }
        qv = (_Float16)(qo * LOG2E); kv = (_Float16)ko;
      }
      Qp[obase + i] = qv; Kp[obase + i] = kv;
    }
    if (i < DPADV) {
      _Float16 vv = (_Float16)0.f;
      if (i < HDIM) vv = (_Float16)(((t == 0) ? v0 : v1) * rv);
      Vp[obV + i] = vv;
    }
  }
}

// ---------------- V transpose: [bh][p][80] -> [bh][80][4096], d=72 := 1 ----
// Ones in row 72 make PV's column 72 accumulate the softmax denominator.
__global__ __launch_bounds__(256) void k_vtrans(
    const _Float16* __restrict__ Vp, _Float16* __restrict__ VtG) {
  __shared__ _Float16 T[DPADV * 72];
  int tid = threadIdx.x;
  int pt = blockIdx.x, bh = blockIdx.y;
  long long src = (long long)bh * PP * DPADV + (long long)pt * 64 * DPADV;
#pragma unroll
  for (int pp = 0; pp < 3; ++pp) {
    int c = tid + pp * 256;
    if (c < 640) {
      int r = c / 10, ds = c % 10;
      half8 v = *(const half8*)(Vp + src + r * DPADV + ds * 8);
#pragma unroll
      for (int j = 0; j < 8; ++j) T[(ds * 8 + j) * 72 + r] = v[j];
    }
  }
  __syncthreads();
  long long dst = (long long)bh * DPADV * PP + (long long)pt * 64;
#pragma unroll
  for (int pp = 0; pp < 3; ++pp) {
    int c = tid + pp * 256;
    if (c < 640) {
      int d = c >> 3, ps = (c & 7) * 8;
      half8 v = *(const half8*)(T + d * 72 + ps);
      if (d == 72) {
#pragma unroll
        for (int j = 0; j < 8; ++j) v[j] = (_Float16)1.f;
      }
      *(half8*)(VtG + dst + (long long)d * PP + ps) = v;
    }
  }
}

// ---------------- flash attention: TQ=128, V^T pre-staged, MFMA l-sum -------
// Block: 256 thr (4 waves), each wave 32 q-rows (2 row-blocks of 16), TK=64.
// S computed TRANSPOSED (mfma(K,Q)); Q pre-scaled by log2e -> exp2 softmax
// via raw v_exp_f32 (__builtin_amdgcn_exp2f; plain exp2f is slow libm).
// K-dim 80 via 3x mfma_x32, third chunk quad-predicated (only proven layout).
// Grid: x = head (pins all q-tiles of a head to one XCD), y = q-tile.
#define TK 64
#define NT (PP / TK)
#define LDK 80    // K rows, no pad (stride 160 B, 16B-aligned)
#define LDV 72    // V^T 80x72, P 32x72/wave
__global__ __launch_bounds__(256) void k_flash(
    const _Float16* __restrict__ Qp, const _Float16* __restrict__ Kp,
    const _Float16* __restrict__ VtG, _Float16* __restrict__ Oat) {
  __shared__ _Float16 Kl[TK * LDK];         // 10,240 B
  __shared__ _Float16 Vt[DPADV * LDV];      // 11,520 B
  __shared__ _Float16 Pl[128 * LDV];        // 18,432 B
  int tid = threadIdx.x, wave = tid >> 6, lane = tid & 63;
  int quad = lane >> 4, l16 = lane & 15;
  int bh = blockIdx.x, qt = blockIdx.y;
  const long long headoff = (long long)bh * PP * DPAD;
  const long long vhead   = (long long)bh * DPADV * PP;

  half8 zh8;
#pragma unroll
  for (int j = 0; j < 8; ++j) zh8[j] = (_Float16)0.f;

  half8 qf[2][3];
#pragma unroll
  for (int mb = 0; mb < 2; ++mb) {
    int qrow = qt * 128 + wave * 32 + mb * 16 + l16;
    const _Float16* qp = Qp + headoff + (long long)qrow * DPAD;
#pragma unroll
    for (int ck = 0; ck < 2; ++ck)
      qf[mb][ck] = *(const half8*)(qp + ck * 32 + quad * 8);
    qf[mb][2] = zh8;
    if (quad < 2) qf[mb][2] = *(const half8*)(qp + 64 + quad * 8);
  }

  floatx4 O[2][5];
  floatx4 z4 = {0.f, 0.f, 0.f, 0.f};
#pragma unroll
  for (int mb = 0; mb < 2; ++mb)
#pragma unroll
    for (int d = 0; d < 5; ++d) O[mb][d] = z4;
  float m_i[2];
  m_i[0] = -1e30f; m_i[1] = -1e30f;
  _Float16* Pw = Pl + wave * 32 * LDV;

  // T14 async-STAGE: global->reg issue early, reg->LDS write after barrier.
  half8 kreg[3], vreg[3];
  {
    const _Float16* Ksrc = Kp + headoff;
    const _Float16* Vsrc = VtG + vhead;
#pragma unroll
    for (int pp = 0; pp < 3; ++pp) {
      int c = tid + pp * 256;
      if (c < 640)
        kreg[pp] = *(const half8*)(Ksrc + c * 8);
    }
#pragma unroll
    for (int pp = 0; pp < 3; ++pp) {
      int c = tid + pp * 256;
      if (c < 640)
        vreg[pp] = *(const half8*)(Vsrc + (long long)(c >> 3) * PP + (c & 7) * 8);
    }
  }

  for (int kt = 0; kt < NT; ++kt) {
    __syncthreads();   // prior-iter reads of Kl/Vt done before restaging
#pragma unroll
    for (int pp = 0; pp < 3; ++pp) {        // K: 640 16B chunks (64x80)
      int c = tid + pp * 256;
      if (c < 640)
        *(half8*)(Kl + (c / 10) * LDK + (c % 10) * 8) = kreg[pp];
    }
#pragma unroll
    for (int pp = 0; pp < 3; ++pp) {        // V^T: 640 16B chunks (80x64)
      int c = tid + pp * 256;
      if (c < 640)
        *(half8*)(Vt + (c >> 3) * LDV + (c & 7) * 8) = vreg[pp];
    }
    __syncthreads();

    // issue next tile's global loads; latency hides under compute below
    {
      int ktn = (kt + 1 < NT) ? kt + 1 : kt;
      const _Float16* Ksrc = Kp + headoff + (long long)ktn * TK * DPAD;
      const _Float16* Vsrc = VtG + vhead + ktn * TK;
#pragma unroll
      for (int pp = 0; pp < 3; ++pp) {
        int c = tid + pp * 256;
        if (c < 640)
          kreg[pp] = *(const half8*)(Ksrc + c * 8);
      }
#pragma unroll
      for (int pp = 0; pp < 3; ++pp) {
        int c = tid + pp * 256;
        if (c < 640)
          vreg[pp] = *(const half8*)(Vsrc + (long long)(c >> 3) * PP + (c & 7) * 8);
      }
    }

    // S^T = K Q^T: lane holds S[q = mb*16+l16][key = nb*16+quad*4+r]
    floatx4 sb[2][4];
    __builtin_amdgcn_s_setprio(1);
#pragma unroll
    for (int nb = 0; nb < 4; ++nb) {
      const _Float16* kp = Kl + (nb * 16 + l16) * LDK;
      half8 kf0 = *(const half8*)(kp + quad * 8);
      half8 kf1 = *(const half8*)(kp + 32 + quad * 8);
      half8 kf2 = zh8;
      if (quad < 2) kf2 = *(const half8*)(kp + 64 + quad * 8);
#pragma unroll
      for (int mb = 0; mb < 2; ++mb) {
        floatx4 a = __builtin_amdgcn_mfma_f32_16x16x32_f16(kf0, qf[mb][0], z4, 0, 0, 0);
        a = __builtin_amdgcn_mfma_f32_16x16x32_f16(kf1, qf[mb][1], a, 0, 0, 0);
        a = __builtin_amdgcn_mfma_f32_16x16x32_f16(kf2, qf[mb][2], a, 0, 0, 0);
        sb[mb][nb] = a;
      }
    }
    __builtin_amdgcn_s_setprio(0);

    // online softmax in exp2 domain (Q pre-scaled by log2e).
    // Max via nested fmax triples -> v_max3_f32 (T17).
    // T13 defer-max: skip O-rescale while tile max stays within 11.5 of m_i.
#pragma unroll
    for (int mb = 0; mb < 2; ++mb) {
      float t1 = fmaxf(fmaxf(sb[mb][0][0], sb[mb][0][1]), sb[mb][0][2]);
      float t2 = fmaxf(fmaxf(sb[mb][0][3], sb[mb][1][0]), sb[mb][1][1]);
      float t3 = fmaxf(fmaxf(sb[mb][1][2], sb[mb][1][3]), sb[mb][2][0]);
      float t4 = fmaxf(fmaxf(sb[mb][2][1], sb[mb][2][2]), sb[mb][2][3]);
      float t5 = fmaxf(fmaxf(sb[mb][3][0], sb[mb][3][1]), sb[mb][3][2]);
      float t = fmaxf(fmaxf(t1, t2), t3);
      t = fmaxf(fmaxf(t, t4), t5);
      t = fmaxf(t, sb[mb][3][3]);
      t = fmaxf(t, __shfl_xor(t, 16));
      t = fmaxf(t, __shfl_xor(t, 32));
      if (!__all(t <= m_i[mb] + 11.5f)) {
        float mnew = fmaxf(m_i[mb], t);
        float al = __builtin_amdgcn_exp2f(m_i[mb] - mnew);
        m_i[mb] = mnew;
        // transpose al (per q=l16) to O's row axis (q=quad*4+r): source lane
        // (same quad group) with l16 == quad*4+r holds that row's factor.
        float alT[4];
#pragma unroll
        for (int r = 0; r < 4; ++r)
          alT[r] = __shfl(al, (lane & 48) + quad * 4 + r);
#pragma unroll
        for (int d = 0; d < 5; ++d)
#pragma unroll
          for (int r = 0; r < 4; ++r) O[mb][d][r] *= alT[r];
      }
      float mi = m_i[mb];
      // P write: 4 consecutive keys per lane -> one b64 per (mb,nb)
#pragma unroll
      for (int nb = 0; nb < 4; ++nb) {
        half4 w;
#pragma unroll
        for (int r = 0; r < 4; ++r)
          w[r] = (_Float16)__builtin_amdgcn_exp2f(sb[mb][nb][r] - mi);
        *(half4*)(Pw + (mb * 16 + l16) * LDV + nb * 16 + quad * 4) = w;
      }
    }

    // O += P V  (V-frags reused across mb; col 72 accumulates l)
    __builtin_amdgcn_s_setprio(1);
#pragma unroll
    for (int ck2 = 0; ck2 < 2; ++ck2) {
      half8 pf0 = *(const half8*)(Pw + l16 * LDV + ck2 * 32 + quad * 8);
      half8 pf1 = *(const half8*)(Pw + (16 + l16) * LDV + ck2 * 32 + quad * 8);
#pragma unroll
      for (int d = 0; d < 5; ++d) {
        half8 vf = *(const half8*)(Vt + (d * 16 + l16) * LDV + ck2 * 32 + quad * 8);
        O[0][d] = __builtin_amdgcn_mfma_f32_16x16x32_f16(pf0, vf, O[0][d], 0, 0, 0);
        O[1][d] = __builtin_amdgcn_mfma_f32_16x16x32_f16(pf1, vf, O[1][d], 0, 0, 0);
      }
    }
    __builtin_amdgcn_s_setprio(0);
  }

  // epilogue: l lives in O[mb][4] at l16==8; broadcast within quad, divide.
  int b = bh >> 4, h = bh & 15;
  int src = (lane & 48) + 8;
#pragma unroll
  for (int mb = 0; mb < 2; ++mb) {
    float linv[4];
#pragma unroll
    for (int r = 0; r < 4; ++r)
      linv[r] = 1.f / __shfl(O[mb][4][r], src);
    long long orow = (long long)b * PP + qt * 128 + wave * 32 + mb * 16 + quad * 4;
#pragma unroll
    for (int d = 0; d < 5; ++d) {
      int dd = d * 16 + l16;
      if (dd < HDIM) {
#pragma unroll
        for (int r = 0; r < 4; ++r)
          Oat[(orow + r) * HID + h * HDIM + dd] = (_Float16)(O[mb][d][r] * linv[r]);
      }
    }
  }
}

// ---------------------------------------------------------------------------
extern "C" void kernel_launch(void* const* d_in, const int* in_sizes, int n_in,
                              void* d_out, int out_size, void* d_ws, size_t ws_size,
                              hipStream_t stream) {
  (void)in_sizes; (void)n_in; (void)out_size; (void)ws_size;
  const void* hs   = d_in[0];
  const void* cosp = d_in[1];
  const void* sinp = d_in[2];
  const void* wq   = d_in[3];
  const void* wk   = d_in[4];
  const void* wv   = d_in[5];
  const void* wo   = d_in[6];
  const void* qnw  = d_in[7];
  const void* knw  = d_in[8];

  char* ws = (char*)d_ws;
  size_t off = 0;
  auto take = [&](size_t bytes) -> char* {
    off = (off + 255) & ~(size_t)255;
    char* p = ws + off; off += bytes; return p;
  };
  int* flag        = (int*)take(4);
  _Float16* Xh     = (_Float16*)take((size_t)MR * HID * 2);     // 18.9 MB
  _Float16* Wqkvh  = (_Float16*)take((size_t)NQKV * HID * 2);   // 8.0 MB
  _Float16* Woth   = (_Float16*)take((size_t)HID * HID * 2);    // 2.65 MB
  float* cosf_     = (float*)take((size_t)2 * PP * HDIM * 4);
  float* sinf_     = (float*)take((size_t)2 * PP * HDIM * 4);
  float* qwf       = (float*)take(HDIM * 4);
  float* kwf       = (float*)take(HDIM * 4);
  _Float16* QKVh   = (_Float16*)take((size_t)MR * NQKV * 2);    // 56.6 MB
  _Float16* Kp     = (_Float16*)take((size_t)2 * NHEADS * PP * DPAD * 2);   // 21.0 MB
  _Float16* Vp     = (_Float16*)take((size_t)2 * NHEADS * PP * DPADV * 2);  // 21.0 MB
  // Aliases over dead regions (sequential stream, graph-safe):
  //  - Qp reuses Xh+Wqkvh (26.9 MB >= 21.0 MB; both dead after QKV GEMM)
  //  - Oat reuses QKVh[0 .. 18.9 MB) (QKVh dead after k_norm_rope)
  //  - VtG reuses QKVh[20 MB .. 41 MB) (past Oat, within QKVh's 56.6 MB)
  _Float16* Qp  = Xh;
  _Float16* Oat = QKVh;
  _Float16* VtG = (_Float16*)((char*)QKVh + (size_t)20 * 1024 * 1024);

  k_detect<<<dim3(1), dim3(64), 0, stream>>>(hs, flag);

  long long totalPrep = (long long)MR * HID + (long long)NQKV * HID +
                        (long long)HID * HID + 2LL * 2 * PP * HDIM + 2 * HDIM;
  int prepBlocks = (int)((totalPrep + 255) / 256);
  k_prep<<<dim3(prepBlocks), dim3(256), 0, stream>>>(
      hs, cosp, sinp, wq, wk, wv, wo, qnw, knw, flag,
      Xh, Wqkvh, Woth, cosf_, sinf_, qwf, kwf);

  // QKV = X @ [Wq|Wk|Wv]  (fp16 inputs, fp32 accum, fp16 out)
  k_gemm<<<dim3(NQKV / 128, MR / 128), dim3(256), 0, stream>>>(
      Xh, Wqkvh, NQKV, HID, 0, flag, QKVh);

  k_norm_rope<<<dim3(MR * NHEADS / 4), dim3(256), 0, stream>>>(
      QKVh, cosf_, sinf_, qwf, kwf, Qp, Kp, Vp);

  k_vtrans<<<dim3(PP / 64, 2 * NHEADS), dim3(256), 0, stream>>>(Vp, VtG);

  k_flash<<<dim3(2 * NHEADS, PP / 128), dim3(256), 0, stream>>>(Qp, Kp, VtG, Oat);

  // out = attnout @ Wo  (fp16 inputs, output per detected dtype)
  k_gemm<<<dim3(HID / 128, MR / 128), dim3(256), 0, stream>>>(
      Oat, Woth, HID, HID, 1, flag, d_out);
}